// Round 1
// baseline (1078.618 us; speedup 1.0000x reference)
//
#include <hip/hip_runtime.h>

// GIN forward: lin0 -> 3x [GINConv(sum-agg) -> Linear->BN->ReLU->Linear->BN->ReLU] -> mean-pool
// N=100000 nodes, E=1.6M edges, D=49 (padded to LD=64), NG=512 graphs.
//
// Strategy:
//  - Build CSR (dst-grouped) once per call: histogram + scan + scatter (ws is re-poisoned
//    every call, so this must rerun; it's ~E work).
//  - Aggregation: one wave per node, lane=column, coalesced 256B row gathers, no atomics.
//  - GEMM: one thread per row, W zero-padded [49][52] in LDS (16B-aligned rows for
//    ds_read_b128 broadcast), acc[52] in registers, row streamed from L1.
//  - BN stats fused into GEMM epilogue: wave butterfly reduce + 49-lane atomics.
//  - BN apply fused into next GEMM's input load (scale/shift precomputed in LDS).
//  - Pool: batch is sorted -> per-graph binary search, one wave per graph, no atomics.
//
// Workspace: ~59 MB (h, z: N*64 f32 each; rowptr/fill: N ints; csr: E ints; stats: 768 f32).

#define DV 49
#define LD 64
#define DIN 56
#define NGR 512
#define NLAY 3
#define SCAN_ELEMS 2048

__global__ void k_zero(int* __restrict__ rowptr, int* __restrict__ fill,
                       float* __restrict__ stats, int N) {
    int i = blockIdx.x * blockDim.x + threadIdx.x;
    int stride = gridDim.x * blockDim.x;
    for (int j = i; j < N + 1; j += stride) rowptr[j] = 0;
    for (int j = i; j < N; j += stride) fill[j] = 0;
    for (int j = i; j < NLAY * 2 * 128; j += stride) stats[j] = 0.f;
}

__global__ void k_hist(const int* __restrict__ dst, int E, int* __restrict__ rowptr) {
    int i = blockIdx.x * blockDim.x + threadIdx.x;
    int stride = gridDim.x * blockDim.x;
    for (int e = i; e < E; e += stride) atomicAdd(&rowptr[dst[e] + 1], 1);
}

__global__ void k_scan1(const int* __restrict__ data, int M, int* __restrict__ partial) {
    __shared__ int sm[256];
    int b = blockIdx.x, t = threadIdx.x;
    long base = (long)b * SCAN_ELEMS;
    int s = 0;
    for (int i = t; i < SCAN_ELEMS; i += 256) {
        long idx = base + i;
        if (idx < M) s += data[idx];
    }
    sm[t] = s;
    __syncthreads();
    for (int off = 128; off > 0; off >>= 1) {
        if (t < off) sm[t] += sm[t + off];
        __syncthreads();
    }
    if (t == 0) partial[b] = sm[0];
}

__global__ void k_scan2(int* __restrict__ partial, int nb) {
    __shared__ int sm[256];
    int t = threadIdx.x;
    int v = (t < nb) ? partial[t] : 0;
    sm[t] = v;
    __syncthreads();
    for (int off = 1; off < 256; off <<= 1) {
        int x = (t >= off) ? sm[t - off] : 0;
        __syncthreads();
        sm[t] += x;
        __syncthreads();
    }
    if (t < nb) partial[t] = sm[t] - v;  // exclusive
}

__global__ void k_scan3(int* __restrict__ data, int M, const int* __restrict__ partial) {
    __shared__ int sm[256];
    int b = blockIdx.x, t = threadIdx.x;
    long base = (long)b * SCAN_ELEMS + (long)t * 8;
    int vals[8];
    int s = 0;
#pragma unroll
    for (int i = 0; i < 8; i++) {
        long idx = base + i;
        int v = (idx < M) ? data[idx] : 0;
        vals[i] = v;
        s += v;
    }
    sm[t] = s;
    __syncthreads();
    for (int off = 1; off < 256; off <<= 1) {
        int x = (t >= off) ? sm[t - off] : 0;
        __syncthreads();
        sm[t] += x;
        __syncthreads();
    }
    int run = sm[t] - s + partial[b];  // exclusive prefix for this thread
#pragma unroll
    for (int i = 0; i < 8; i++) {
        long idx = base + i;
        run += vals[i];
        if (idx < M) data[idx] = run;  // inclusive scan in-place
    }
}

__global__ void k_scatter(const int* __restrict__ src, const int* __restrict__ dst, int E,
                          const int* __restrict__ rowptr, int* __restrict__ fill,
                          int* __restrict__ csr) {
    int i = blockIdx.x * blockDim.x + threadIdx.x;
    int stride = gridDim.x * blockDim.x;
    for (int e = i; e < E; e += stride) {
        int d = dst[e];
        int pos = rowptr[d] + atomicAdd(&fill[d], 1);
        csr[pos] = src[e];
    }
}

__global__ void k_lin0(const float* __restrict__ x, const float* __restrict__ W0,
                       const float* __restrict__ b0, float* __restrict__ h, int N) {
    __shared__ __align__(16) float Ws[DIN * 52];
    __shared__ float pb[52];
    int t = threadIdx.x;
    for (int i = t; i < DIN * 52; i += 256) {
        int k = i / 52, c = i - k * 52;
        Ws[i] = (c < DV) ? W0[k * DV + c] : 0.f;
    }
    for (int i = t; i < 52; i += 256) pb[i] = (i < DV) ? b0[i] : 0.f;
    __syncthreads();
    int n = blockIdx.x * 256 + t;
    if (n >= N) return;
    float acc[52];
#pragma unroll
    for (int c = 0; c < 52; c++) acc[c] = pb[c];
    const float* xr = x + (size_t)n * DIN;
    for (int k = 0; k < DIN; k++) {
        float xv = xr[k];
#pragma unroll
        for (int c4 = 0; c4 < 13; c4++) {
            float4 w = *(const float4*)&Ws[k * 52 + c4 * 4];
            acc[c4 * 4 + 0] = fmaf(xv, w.x, acc[c4 * 4 + 0]);
            acc[c4 * 4 + 1] = fmaf(xv, w.y, acc[c4 * 4 + 1]);
            acc[c4 * 4 + 2] = fmaf(xv, w.z, acc[c4 * 4 + 2]);
            acc[c4 * 4 + 3] = fmaf(xv, w.w, acc[c4 * 4 + 3]);
        }
    }
    float* hr = h + (size_t)n * LD;
#pragma unroll
    for (int c4 = 0; c4 < 13; c4++) {
        float4 o;
        o.x = acc[c4 * 4 + 0]; o.y = acc[c4 * 4 + 1];
        o.z = acc[c4 * 4 + 2]; o.w = acc[c4 * 4 + 3];
        *(float4*)&hr[c4 * 4] = o;
    }
    float4 zz = make_float4(0.f, 0.f, 0.f, 0.f);
    *(float4*)&hr[52] = zz;
    *(float4*)&hr[56] = zz;
    *(float4*)&hr[60] = zz;
}

// One wave per node; lane = padded column. acc = (1+eps)*h[n] + sum over in-edges h[src].
__global__ void k_agg(const float* __restrict__ h, float* __restrict__ z,
                      const int* __restrict__ rowptr, const int* __restrict__ csr,
                      const float* __restrict__ eps_gin, int l, int N) {
    int wave = threadIdx.x >> 6;
    int lane = threadIdx.x & 63;
    int n = blockIdx.x * 4 + wave;
    if (n >= N) return;
    float eps1 = 1.f + eps_gin[l];
    int start = rowptr[n], end = rowptr[n + 1];
    float acc = eps1 * h[(size_t)n * LD + lane];
    int deg = end - start;
    for (int base = 0; base < deg; base += 64) {
        int m = min(64, deg - base);
        int sv = (lane < m) ? csr[start + base + lane] : 0;
        int e = 0;
        for (; e + 4 <= m; e += 4) {
            int s0 = __shfl(sv, e), s1 = __shfl(sv, e + 1);
            int s2 = __shfl(sv, e + 2), s3 = __shfl(sv, e + 3);
            float v0 = h[(size_t)s0 * LD + lane];
            float v1 = h[(size_t)s1 * LD + lane];
            float v2 = h[(size_t)s2 * LD + lane];
            float v3 = h[(size_t)s3 * LD + lane];
            acc += v0; acc += v1; acc += v2; acc += v3;
        }
        for (; e < m; e++) {
            int s = __shfl(sv, e);
            acc += h[(size_t)s * LD + lane];
        }
    }
    z[(size_t)n * LD + lane] = acc;
}

// One thread per row. Optional BN+ReLU applied to the input on load (stats of the
// PREVIOUS linear), optional column sum/sumsq accumulation of the output (for the
// NEXT BN). in/out may alias (same row, read-then-write per thread) -> no __restrict__.
template <bool BN_IN, bool STATS_OUT>
__global__ void k_gemm(const float* in, float* out,
                       const float* __restrict__ W, const float* __restrict__ bias,
                       const float* __restrict__ gam, const float* __restrict__ bet,
                       const float* __restrict__ statsIn, float* __restrict__ statsOut,
                       float invN, int N) {
    __shared__ __align__(16) float Ws[DV * 52];
    __shared__ float pb[52];
    __shared__ float sc[DV], sh[DV];
    int t = threadIdx.x;
    for (int i = t; i < DV * 52; i += 256) {
        int k = i / 52, c = i - k * 52;
        Ws[i] = (c < DV) ? W[k * DV + c] : 0.f;
    }
    for (int i = t; i < 52; i += 256) pb[i] = (i < DV) ? bias[i] : 0.f;
    if (BN_IN) {
        if (t < DV) {
            float mu = statsIn[t] * invN;
            float var = statsIn[64 + t] * invN - mu * mu;
            float s = gam[t] * rsqrtf(var + 1e-5f);
            sc[t] = s;
            sh[t] = bet[t] - mu * s;
        }
    }
    __syncthreads();
    int n = blockIdx.x * 256 + t;
    bool active = (n < N);
    float acc[52];
#pragma unroll
    for (int c = 0; c < 52; c++) acc[c] = pb[c];
    if (active) {
        const float* rowp = in + (size_t)n * LD;
        for (int k = 0; k < DV; k++) {
            float xv = rowp[k];
            if (BN_IN) xv = fmaxf(0.f, fmaf(xv, sc[k], sh[k]));
#pragma unroll
            for (int c4 = 0; c4 < 13; c4++) {
                float4 w = *(const float4*)&Ws[k * 52 + c4 * 4];
                acc[c4 * 4 + 0] = fmaf(xv, w.x, acc[c4 * 4 + 0]);
                acc[c4 * 4 + 1] = fmaf(xv, w.y, acc[c4 * 4 + 1]);
                acc[c4 * 4 + 2] = fmaf(xv, w.z, acc[c4 * 4 + 2]);
                acc[c4 * 4 + 3] = fmaf(xv, w.w, acc[c4 * 4 + 3]);
            }
        }
        float* orow = out + (size_t)n * LD;
#pragma unroll
        for (int c4 = 0; c4 < 13; c4++) {
            float4 o;
            o.x = acc[c4 * 4 + 0]; o.y = acc[c4 * 4 + 1];
            o.z = acc[c4 * 4 + 2]; o.w = acc[c4 * 4 + 3];
            *(float4*)&orow[c4 * 4] = o;
        }
        float4 zz = make_float4(0.f, 0.f, 0.f, 0.f);
        *(float4*)&orow[52] = zz;
        *(float4*)&orow[56] = zz;
        *(float4*)&orow[60] = zz;
    }
    if (STATS_OUT) {
        // wave butterfly per column; lane c keeps column c's totals; 2 atomics/wave.
        float myS = 0.f, myQ = 0.f;
        int lane = t & 63;
#pragma unroll
        for (int c = 0; c < DV; c++) {
            float v = active ? acc[c] : 0.f;
            float s = v, q = v * v;
#pragma unroll
            for (int off = 32; off > 0; off >>= 1) {
                s += __shfl_xor(s, off);
                q += __shfl_xor(q, off);
            }
            if (lane == c) { myS = s; myQ = q; }
        }
        if (lane < DV) {
            atomicAdd(&statsOut[lane], myS);
            atomicAdd(&statsOut[64 + lane], myQ);
        }
    }
}

__global__ void k_bnrelu(const float* __restrict__ in, float* __restrict__ out,
                         const float* __restrict__ gam, const float* __restrict__ bet,
                         const float* __restrict__ stats, float invN, long total) {
    long i = (long)(blockIdx.x * blockDim.x + threadIdx.x);
    long stride = (long)gridDim.x * blockDim.x;
    for (; i < total; i += stride) {
        int c = (int)(i & (LD - 1));
        float v = 0.f;
        if (c < DV) {
            float mu = stats[c] * invN;
            float var = stats[64 + c] * invN - mu * mu;
            float s = gam[c] * rsqrtf(var + 1e-5f);
            float tt = bet[c] - mu * s;
            v = fmaxf(0.f, fmaf(in[i], s, tt));
        }
        out[i] = v;
    }
}

// batch is sorted: one wave per graph, binary-search the node range. No atomics.
__global__ void k_pool(const float* __restrict__ h, const int* __restrict__ batch,
                       float* __restrict__ out, int N) {
    int g = blockIdx.x;
    int lane = threadIdx.x;
    int lo, hi;
    {
        int a = 0, b = N;
        while (a < b) { int mid = (a + b) >> 1; if (batch[mid] < g) a = mid + 1; else b = mid; }
        lo = a;
    }
    {
        int a = lo, b = N;
        while (a < b) { int mid = (a + b) >> 1; if (batch[mid] < g + 1) a = mid + 1; else b = mid; }
        hi = a;
    }
    float acc = 0.f;
    for (int n2 = lo; n2 < hi; n2++) acc += h[(size_t)n2 * LD + lane];
    float cnt = (float)max(hi - lo, 1);
    if (lane < DV) out[g * DV + lane] = acc / cnt;
}

extern "C" void kernel_launch(void* const* d_in, const int* in_sizes, int n_in,
                              void* d_out, int out_size, void* d_ws, size_t ws_size,
                              hipStream_t stream) {
    const float* x = (const float*)d_in[0];
    const float* W0 = (const float*)d_in[1];
    const float* b0 = (const float*)d_in[2];
    const float* W1 = (const float*)d_in[3];
    const float* b1 = (const float*)d_in[4];
    const float* g1 = (const float*)d_in[5];
    const float* be1 = (const float*)d_in[6];
    const float* W2 = (const float*)d_in[7];
    const float* b2 = (const float*)d_in[8];
    const float* g2 = (const float*)d_in[9];
    const float* be2 = (const float*)d_in[10];
    const float* eps_gin = (const float*)d_in[11];
    const int* edge_index = (const int*)d_in[12];
    const int* batch = (const int*)d_in[13];
    float* out = (float*)d_out;

    int N = in_sizes[0] / DIN;
    int E = in_sizes[12] / 2;
    const int* esrc = edge_index;
    const int* edst = edge_index + E;

    char* ws = (char*)d_ws;
    size_t off = 0;
    auto alloc = [&](size_t bytes) -> void* {
        void* p = ws + off;
        off = (off + bytes + 255) & ~(size_t)255;
        return p;
    };
    float* h = (float*)alloc((size_t)N * LD * 4);
    float* z = (float*)alloc((size_t)N * LD * 4);
    int* rowptr = (int*)alloc((size_t)(N + 1) * 4);
    int* fill = (int*)alloc((size_t)N * 4);
    int* csr = (int*)alloc((size_t)E * 4);
    int* partial = (int*)alloc(1024 * 4);
    float* stats = (float*)alloc(NLAY * 2 * 128 * 4);
    (void)ws_size;  // needs ~59 MB

    float invN = 1.f / (float)N;
    int M = N + 1;
    int nb = (M + SCAN_ELEMS - 1) / SCAN_ELEMS;

    k_zero<<<512, 256, 0, stream>>>(rowptr, fill, stats, N);
    k_hist<<<2048, 256, 0, stream>>>(edst, E, rowptr);
    k_scan1<<<nb, 256, 0, stream>>>(rowptr, M, partial);
    k_scan2<<<1, 256, 0, stream>>>(partial, nb);
    k_scan3<<<nb, 256, 0, stream>>>(rowptr, M, partial);
    k_scatter<<<2048, 256, 0, stream>>>(esrc, edst, E, rowptr, fill, csr);
    k_lin0<<<(N + 255) / 256, 256, 0, stream>>>(x, W0, b0, h, N);

    for (int l = 0; l < NLAY; l++) {
        float* S1 = stats + (l * 2 + 0) * 128;
        float* S2 = stats + (l * 2 + 1) * 128;
        k_agg<<<(N + 3) / 4, 256, 0, stream>>>(h, z, rowptr, csr, eps_gin, l, N);
        k_gemm<false, true><<<(N + 255) / 256, 256, 0, stream>>>(
            z, z, W1 + (size_t)l * DV * DV, b1 + l * DV,
            nullptr, nullptr, nullptr, S1, invN, N);
        k_gemm<true, true><<<(N + 255) / 256, 256, 0, stream>>>(
            z, z, W2 + (size_t)l * DV * DV, b2 + l * DV,
            g1 + l * DV, be1 + l * DV, S1, S2, invN, N);
        k_bnrelu<<<4096, 256, 0, stream>>>(z, h, g2 + l * DV, be2 + l * DV, S2, invN,
                                           (long)N * LD);
    }
    k_pool<<<NGR, 64, 0, stream>>>(h, batch, out, N);
}